// Round 2
// baseline (4875.858 us; speedup 1.0000x reference)
//
#include <hip/hip_runtime.h>

// VACF: vel [T=10000, N=1000, 3] fp32, window W=100.
// out[t] = sum_{i<T-t} sum_j x[i][j]*x[i+t][j] / ((T-t)*C),  C = 3000.
//
// Round 2: acc[100] spilled to scratch (WRITE_SIZE 496 MB, VGPR=84).
// Fix: process lags in NG=2 groups of WG=50 so acc+base+win ~ 97 VGPRs
// fits at 4 waves/EU without spills. Zero-padding rows >= T is exact.

#define T_DIM 10000
#define C_DIM 3000
#define W 100
#define WG 50         // lags per group
#define NG 2          // groups (NG*WG == W)
#define R 16          // base rows per chunk; T_DIM % R == 0 (625 chunks)
#define NSEG 85       // time segments -> grid.y (12*85 = 1020 blocks ~ 4/CU)
#define NCGRP 12      // ceil(C_DIM / 256)

__global__ __launch_bounds__(256, 4)
void vacf_accum(const float* __restrict__ X, float* __restrict__ partial) {
    const int tid  = threadIdx.x;
    const int lane = tid & 63;
    const int wv   = tid >> 6;
    const int j    = blockIdx.x * 256 + tid;
    const bool active = (j < C_DIM);
    const int jj  = active ? j : (C_DIM - 1);   // clamp; inactive zeroed via base
    const int seg = blockIdx.y;

    __shared__ float part[4][WG];

    #pragma unroll 1
    for (int g = 0; g < NG; ++g) {
        const int t0 = g * WG;

        float acc[WG];
        #pragma unroll
        for (int t = 0; t < WG; ++t) acc[t] = 0.f;

        #pragma unroll 1
        for (int c = seg; c < T_DIM / R; c += NSEG) {
            const int i0 = c * R;
            float base[R], win[R];
            // base rows i0..i0+R-1 always < T_DIM
            #pragma unroll
            for (int r = 0; r < R; ++r) {
                float v = X[(size_t)(i0 + r) * C_DIM + jj];
                base[r] = active ? v : 0.f;
            }
            // window invariant: win[m % R] holds x[i0 + m] for m in [t, t+R)
            #pragma unroll
            for (int r = 0; r < R; ++r) {
                const int row = i0 + t0 + r;
                win[(t0 + r) % R] = (row < T_DIM) ? X[(size_t)row * C_DIM + jj] : 0.f;
            }
            #pragma unroll
            for (int tt = 0; tt < WG; ++tt) {
                const int t = t0 + tt;
                #pragma unroll
                for (int r = 0; r < R; ++r) {
                    acc[tt] += base[r] * win[(t + r) % R];
                }
                if (tt < WG - 1) {
                    const int row = i0 + t + R;              // next window entry
                    win[t % R] = (row < T_DIM) ? X[(size_t)row * C_DIM + jj] : 0.f;
                }
            }
        }

        // per-lag wave butterfly -> 4-wave LDS combine -> 1 atomic/lag/block
        #pragma unroll
        for (int tt = 0; tt < WG; ++tt) {
            float v = acc[tt];
            #pragma unroll
            for (int m = 1; m < 64; m <<= 1) v += __shfl_xor(v, m, 64);
            if (lane == 0) part[wv][tt] = v;
        }
        __syncthreads();
        if (tid < WG) {
            float s = part[0][tid] + part[1][tid] + part[2][tid] + part[3][tid];
            atomicAdd(&partial[t0 + tid], s);
        }
        __syncthreads();   // protect part[] before next group reuses it
    }
}

__global__ void vacf_scale(const float* __restrict__ partial, float* __restrict__ out) {
    int t = threadIdx.x;
    if (t < W) out[t] = partial[t] / ((float)(T_DIM - t) * (float)C_DIM);
}

extern "C" void kernel_launch(void* const* d_in, const int* in_sizes, int n_in,
                              void* d_out, int out_size, void* d_ws, size_t ws_size,
                              hipStream_t stream) {
    const float* X = (const float*)d_in[0];
    float* out = (float*)d_out;
    float* ws  = (float*)d_ws;

    hipMemsetAsync(ws, 0, W * sizeof(float), stream);
    dim3 grid(NCGRP, NSEG);
    vacf_accum<<<grid, 256, 0, stream>>>(X, ws);
    vacf_scale<<<1, 128, 0, stream>>>(ws, out);
}

// Round 3
// 4395.296 us; speedup vs baseline: 1.1093x; 1.1093x over previous
//
#include <hip/hip_runtime.h>

// VACF: vel [T=10000, N=1000, 3] fp32, window W=100.
// out[t] = sum_{i<T-t} sum_j x[i][j]*x[i+t][j] / ((T-t)*C),  C = 3000.
//
// Round 3: compiler VGPR cap is ~256/min_waves_per_EU (empirical:
// bounds(256,3)->84, bounds(256,4)->64). Need ~110 regs for
// acc[50]+base[16]+win[16]+misc, so bounds(256,2) -> cap 128, and the
// HW still runs 4 waves/EU at <=128 VGPRs. Zero-padding rows >= T is exact.

#define T_DIM 10000
#define C_DIM 3000
#define W 100
#define WG 50         // lags per group
#define NG 2          // groups (NG*WG == W)
#define R 16          // base rows per chunk; T_DIM % R == 0 (625 chunks)
#define NSEG 85       // time segments -> grid.y (12*85 = 1020 blocks ~ 4/CU)
#define NCGRP 12      // ceil(C_DIM / 256)

__global__ __launch_bounds__(256, 2)
void vacf_accum(const float* __restrict__ X, float* __restrict__ partial) {
    const int tid  = threadIdx.x;
    const int lane = tid & 63;
    const int wv   = tid >> 6;
    const int j    = blockIdx.x * 256 + tid;
    const bool active = (j < C_DIM);
    const int jj  = active ? j : (C_DIM - 1);   // clamp; inactive lanes give 0 via base
    const int seg = blockIdx.y;

    __shared__ float part[4][WG];

    #pragma unroll 1
    for (int g = 0; g < NG; ++g) {
        const int t0 = g * WG;

        float acc[WG];
        #pragma unroll
        for (int t = 0; t < WG; ++t) acc[t] = 0.f;

        #pragma unroll 1
        for (int c = seg; c < T_DIM / R; c += NSEG) {
            const int i0 = c * R;
            float base[R], win[R];
            // base rows i0..i0+R-1 always < T_DIM
            #pragma unroll
            for (int r = 0; r < R; ++r) {
                float v = X[(size_t)(i0 + r) * C_DIM + jj];
                base[r] = active ? v : 0.f;
                if (g == 0) win[r] = v;          // group 0: window starts at base rows
            }
            if (g != 0) {
                // window invariant: win[m % R] holds x[i0 + m] for m in [t0, t0+R)
                #pragma unroll
                for (int r = 0; r < R; ++r) {
                    const int row = i0 + t0 + r;
                    win[(t0 + r) % R] = (row < T_DIM) ? X[(size_t)row * C_DIM + jj] : 0.f;
                }
            }
            #pragma unroll
            for (int tt = 0; tt < WG; ++tt) {
                const int t = t0 + tt;
                #pragma unroll
                for (int r = 0; r < R; ++r) {
                    acc[tt] += base[r] * win[(t + r) % R];
                }
                if (tt < WG - 1) {
                    const int row = i0 + t + R;              // next window entry
                    win[t % R] = (row < T_DIM) ? X[(size_t)row * C_DIM + jj] : 0.f;
                }
            }
        }

        // per-lag wave butterfly -> 4-wave LDS combine -> 1 atomic/lag/block
        #pragma unroll
        for (int tt = 0; tt < WG; ++tt) {
            float v = acc[tt];
            #pragma unroll
            for (int m = 1; m < 64; m <<= 1) v += __shfl_xor(v, m, 64);
            if (lane == 0) part[wv][tt] = v;
        }
        __syncthreads();
        if (tid < WG) {
            float s = part[0][tid] + part[1][tid] + part[2][tid] + part[3][tid];
            atomicAdd(&partial[t0 + tid], s);
        }
        __syncthreads();   // protect part[] before next group reuses it
    }
}

__global__ void vacf_scale(const float* __restrict__ partial, float* __restrict__ out) {
    int t = threadIdx.x;
    if (t < W) out[t] = partial[t] / ((float)(T_DIM - t) * (float)C_DIM);
}

extern "C" void kernel_launch(void* const* d_in, const int* in_sizes, int n_in,
                              void* d_out, int out_size, void* d_ws, size_t ws_size,
                              hipStream_t stream) {
    const float* X = (const float*)d_in[0];
    float* out = (float*)d_out;
    float* ws  = (float*)d_ws;

    hipMemsetAsync(ws, 0, W * sizeof(float), stream);
    dim3 grid(NCGRP, NSEG);
    vacf_accum<<<grid, 256, 0, stream>>>(X, ws);
    vacf_scale<<<1, 128, 0, stream>>>(ws, out);
}

// Round 4
// 322.438 us; speedup vs baseline: 15.1218x; 13.6314x over previous
//
#include <hip/hip_runtime.h>

// VACF: vel [T=10000, N=1000, 3] fp32, window W=100.
// out[t] = sum_{i<T-t} sum_j x[i][j]*x[i+t][j] / ((T-t)*C),  C = 3000.
//
// Round 4: R3 still spilled (WRITE 9.25 GB, VGPR pegged at 128): 82 array
// regs + ~50 addr/load temps > 128. Fix: split lags over gridDim.z=4 so
// per-thread arrays are acc[25]+base[16]+win[16]=57. Window indexed
// RELATIVE to t0 so all register indices are compile-time (runtime index
// => scratch). Bounds checks hoisted to a chunk-uniform tail path.

#define T_DIM 10000
#define C_DIM 3000
#define W 100
#define WG 25         // lags per block (gridDim.z groups)
#define NG 4          // lag groups; NG*WG == W
#define R 16          // base rows per chunk; T_DIM % R == 0 (625 chunks)
#define NSEG 85       // time segments -> grid.y
#define NCGRP 12      // ceil(C_DIM / 256)

// One chunk: rows [i0, i0+R) x window rows [i0+t0, i0+t0+WG-2+R].
// win[m % R] holds row i0 + t0 + m for m in [tt, tt+R)  (phase relative to t0).
template <bool CHECKED>
__device__ __forceinline__ void chunk_work(const float* __restrict__ X,
                                           int i0, int t0, int jj, bool active,
                                           float* __restrict__ acc) {
    float base[R], win[R];
    #pragma unroll
    for (int r = 0; r < R; ++r) {
        float v = X[(size_t)(i0 + r) * C_DIM + jj];   // base rows always < T_DIM
        base[r] = active ? v : 0.f;
    }
    #pragma unroll
    for (int r = 0; r < R; ++r) {
        const int row = i0 + t0 + r;
        win[r] = (!CHECKED || row < T_DIM) ? X[(size_t)row * C_DIM + jj] : 0.f;
    }
    #pragma unroll
    for (int tt = 0; tt < WG; ++tt) {
        #pragma unroll
        for (int r = 0; r < R; ++r)
            acc[tt] += base[r] * win[(tt + r) % R];
        if (tt < WG - 1) {
            const int row = i0 + t0 + tt + R;         // next window entry
            win[tt % R] = (!CHECKED || row < T_DIM) ? X[(size_t)row * C_DIM + jj] : 0.f;
        }
    }
}

__global__ __launch_bounds__(256, 2)
void vacf_accum(const float* __restrict__ X, float* __restrict__ partial) {
    const int tid  = threadIdx.x;
    const int lane = tid & 63;
    const int wv   = tid >> 6;
    const int j    = blockIdx.x * 256 + tid;
    const bool active = (j < C_DIM);
    const int jj  = active ? j : (C_DIM - 1);   // clamp; inactive lanes give 0 via base
    const int seg = blockIdx.y;
    const int t0  = blockIdx.z * WG;            // lag group offset (runtime, addr only)

    float acc[WG];
    #pragma unroll
    for (int t = 0; t < WG; ++t) acc[t] = 0.f;

    #pragma unroll 1
    for (int c = seg; c < T_DIM / R; c += NSEG) {
        const int i0 = c * R;
        if (i0 + t0 + WG + R - 2 < T_DIM) {
            chunk_work<false>(X, i0, t0, jj, active, acc);
        } else {
            chunk_work<true>(X, i0, t0, jj, active, acc);
        }
    }

    // per-lag wave butterfly -> 4-wave LDS combine -> 1 atomic/lag/block
    __shared__ float part[4][WG];
    #pragma unroll
    for (int tt = 0; tt < WG; ++tt) {
        float v = acc[tt];
        #pragma unroll
        for (int m = 1; m < 64; m <<= 1) v += __shfl_xor(v, m, 64);
        if (lane == 0) part[wv][tt] = v;
    }
    __syncthreads();
    if (tid < WG) {
        float s = part[0][tid] + part[1][tid] + part[2][tid] + part[3][tid];
        atomicAdd(&partial[t0 + tid], s);
    }
}

__global__ void vacf_scale(const float* __restrict__ partial, float* __restrict__ out) {
    int t = threadIdx.x;
    if (t < W) out[t] = partial[t] / ((float)(T_DIM - t) * (float)C_DIM);
}

extern "C" void kernel_launch(void* const* d_in, const int* in_sizes, int n_in,
                              void* d_out, int out_size, void* d_ws, size_t ws_size,
                              hipStream_t stream) {
    const float* X = (const float*)d_in[0];
    float* out = (float*)d_out;
    float* ws  = (float*)d_ws;

    hipMemsetAsync(ws, 0, W * sizeof(float), stream);
    dim3 grid(NCGRP, NSEG, NG);
    vacf_accum<<<grid, 256, 0, stream>>>(X, ws);
    vacf_scale<<<1, 128, 0, stream>>>(ws, out);
}

// Round 5
// 314.178 us; speedup vs baseline: 15.5194x; 1.0263x over previous
//
#include <hip/hip_runtime.h>

// VACF: vel [T=10000, N=1000, 3] fp32, window W=100.
// out[t] = sum_{i<T-t} sum_j x[i][j]*x[i+t][j] / ((T-t)*C),  C = 3000.
//
// Round 5: R4 stalled on the rolling-window load (load->use ~30 cyc vs
// 200-400 cyc latency; VALUBusy 37%). Fix: flat win[40] register window,
// fresh rows batch-loaded 150+ cyc before first use, and CONTIGUOUS
// chunks per block (CPB=5) so 24 of 40 window rows carry over as a
// register shift instead of re-loads (56 -> 32 loads per 400 FMAs).
// Lag split over gridDim.z=4 keeps acc[25] register-resident (R4 lesson:
// arrays + temps must stay well under the 256/min_waves VGPR cap).

#define T_DIM 10000
#define C_DIM 3000
#define W 100
#define WG 25          // lags per block (gridDim.z)
#define NG 4           // lag groups; NG*WG == W
#define R 16           // base rows per chunk
#define SPAN 40        // window span = R + WG - 1
#define CPB 5          // contiguous chunks per block
#define NSEG 125       // (T_DIM/R) / CPB = 625/5
#define NCGRP 12       // ceil(C_DIM / 256)

template <bool CHECKED>
__device__ __forceinline__ float wload(const float* __restrict__ Xj, int row) {
    // row * C_DIM fits in int (3e7); row is wave-uniform -> scalar offset math
    return (!CHECKED || row < T_DIM) ? Xj[row * C_DIM] : 0.f;
}

template <bool CHECKED>
__device__ __forceinline__ void segment_work(const float* __restrict__ Xj,
                                             int i00, int t0, bool active,
                                             float* __restrict__ acc) {
    float win[SPAN];
    float base[R];

    // prologue: full window for chunk 0, rows [i00+t0, i00+t0+SPAN)
    #pragma unroll
    for (int q = 0; q < SPAN; ++q)
        win[q] = wload<CHECKED>(Xj, i00 + t0 + q);

    #pragma unroll 1
    for (int c = 0; c < CPB; ++c) {
        const int i0 = i00 + c * R;

        // base rows [i0, i0+R) — always < T_DIM; issue first for load lead
        #pragma unroll
        for (int r = 0; r < R; ++r) {
            float v = Xj[(i0 + r) * C_DIM];
            base[r] = active ? v : 0.f;
        }

        if (c > 0) {
            // slide window: keep 24 overlap rows in registers
            #pragma unroll
            for (int q = 0; q < SPAN - R; ++q) win[q] = win[q + R];
            // fresh rows [i0+t0+24, i0+t0+40); first used at tt=9
            #pragma unroll
            for (int q = SPAN - R; q < SPAN; ++q)
                win[q] = wload<CHECKED>(Xj, i0 + t0 + q);
        }

        #pragma unroll
        for (int tt = 0; tt < WG; ++tt) {
            #pragma unroll
            for (int r = 0; r < R; ++r)
                acc[tt] += base[r] * win[tt + r];
        }
    }
}

__global__ __launch_bounds__(256, 2)
void vacf_accum(const float* __restrict__ X, float* __restrict__ partial) {
    const int tid  = threadIdx.x;
    const int lane = tid & 63;
    const int wv   = tid >> 6;
    const int j    = blockIdx.x * 256 + tid;
    const bool active = (j < C_DIM);
    const int jj  = active ? j : (C_DIM - 1);   // clamp; inactive zeroed via base
    const float* Xj = X + jj;
    const int t0  = blockIdx.z * WG;            // lag group offset
    const int i00 = blockIdx.y * (CPB * R);     // first base row of segment

    float acc[WG];
    #pragma unroll
    for (int t = 0; t < WG; ++t) acc[t] = 0.f;

    // max row touched = i00 + (CPB-1)*R + t0 + SPAN-1
    const bool tail = (i00 + (CPB - 1) * R + t0 + SPAN - 1) >= T_DIM;
    if (!tail) segment_work<false>(Xj, i00, t0, active, acc);
    else       segment_work<true >(Xj, i00, t0, active, acc);

    // per-lag wave butterfly -> 4-wave LDS combine -> 1 atomic/lag/block
    __shared__ float part[4][WG];
    #pragma unroll
    for (int tt = 0; tt < WG; ++tt) {
        float v = acc[tt];
        #pragma unroll
        for (int m = 1; m < 64; m <<= 1) v += __shfl_xor(v, m, 64);
        if (lane == 0) part[wv][tt] = v;
    }
    __syncthreads();
    if (tid < WG) {
        float s = part[0][tid] + part[1][tid] + part[2][tid] + part[3][tid];
        atomicAdd(&partial[t0 + tid], s);
    }
}

__global__ void vacf_scale(const float* __restrict__ partial, float* __restrict__ out) {
    int t = threadIdx.x;
    if (t < W) out[t] = partial[t] / ((float)(T_DIM - t) * (float)C_DIM);
}

extern "C" void kernel_launch(void* const* d_in, const int* in_sizes, int n_in,
                              void* d_out, int out_size, void* d_ws, size_t ws_size,
                              hipStream_t stream) {
    const float* X = (const float*)d_in[0];
    float* out = (float*)d_out;
    float* ws  = (float*)d_ws;

    hipMemsetAsync(ws, 0, W * sizeof(float), stream);
    dim3 grid(NCGRP, NSEG, NG);
    vacf_accum<<<grid, 256, 0, stream>>>(X, ws);
    vacf_scale<<<1, 128, 0, stream>>>(ws, out);
}

// Round 6
// 313.607 us; speedup vs baseline: 15.5477x; 1.0018x over previous
//
#include <hip/hip_runtime.h>

// VACF: vel [T=10000, N=1000, 3] fp32, window W=100.
// out[t] = sum_{i<T-t} sum_j x[i][j]*x[i+t][j] / ((T-t)*C),  C = 3000.
//
// Round 6: R5's stall was the BASE rows: loaded at chunk top, consumed at
// tt=0 (load->use ~0) -> ~400-900 cyc stall per 950-cyc chunk (VALUBusy 43%).
// Fix: software-pipeline one chunk ahead. At chunk c, issue nbase[16] +
// nfresh[16] for chunk c+1, do chunk c's 400 FMAs, then rotate. Load->use
// distance >= one chunk body (~800 cyc) > HBM-miss latency (~900 close).
// Register budget: acc25+win40+base16+nbase16+nfresh16 = 113 arrays + temps
// ~= 125 vs 128 cap of bounds(256,2). c-loop kept rolled (#pragma unroll 1)
// so the compiler can't hoist all prefetches and blow the budget.
// Fallback if WRITE_SIZE shows spills: WG=20/NG=5.

#define T_DIM 10000
#define C_DIM 3000
#define W 100
#define WG 25          // lags per block (gridDim.z)
#define NG 4           // lag groups; NG*WG == W
#define R 16           // base rows per chunk
#define SPAN 40        // window span = R + WG - 1
#define CPB 5          // contiguous chunks per block
#define NSEG 125       // (T_DIM/R) / CPB
#define NCGRP 12       // ceil(C_DIM / 256)

template <bool CHECKED>
__device__ __forceinline__ float wload(const float* __restrict__ Xj, int row) {
    // row is wave-uniform; row*C_DIM fits in int
    return (!CHECKED || row < T_DIM) ? Xj[row * C_DIM] : 0.f;
}

template <bool CHECKED>
__device__ __forceinline__ void segment_work(const float* __restrict__ Xj,
                                             int i00, int t0, bool active,
                                             float* __restrict__ acc) {
    float win[SPAN], base[R], nbase[R], nfresh[R];

    // prologue (only unhidden loads: once per segment)
    #pragma unroll
    for (int q = 0; q < SPAN; ++q)
        win[q] = wload<CHECKED>(Xj, i00 + t0 + q);
    #pragma unroll
    for (int r = 0; r < R; ++r) {
        float v = Xj[(i00 + r) * C_DIM];       // base rows always < T_DIM
        base[r] = active ? v : 0.f;
    }

    #pragma unroll 1
    for (int c = 0; c < CPB; ++c) {
        const int i0 = i00 + c * R;
        const bool more = (c + 1 < CPB);

        // ---- prefetch chunk c+1 (consumed after this chunk's 400 FMAs) ----
        if (more) {
            #pragma unroll
            for (int r = 0; r < R; ++r) {
                float v = Xj[(i0 + R + r) * C_DIM];   // next base, always < T_DIM
                nbase[r] = active ? v : 0.f;
            }
            #pragma unroll
            for (int q = 0; q < R; ++q)               // next fresh window rows
                nfresh[q] = wload<CHECKED>(Xj, i0 + R + t0 + (SPAN - R) + q);
        }

        // ---- 400 FMAs on fully-resident registers ----
        #pragma unroll
        for (int tt = 0; tt < WG; ++tt) {
            #pragma unroll
            for (int r = 0; r < R; ++r)
                acc[tt] += base[r] * win[tt + r];
        }

        // ---- rotate pipeline registers ----
        if (more) {
            #pragma unroll
            for (int q = 0; q < SPAN - R; ++q) win[q] = win[q + R];
            #pragma unroll
            for (int q = 0; q < R; ++q) win[SPAN - R + q] = nfresh[q];
            #pragma unroll
            for (int r = 0; r < R; ++r) base[r] = nbase[r];
        }
    }
}

__global__ __launch_bounds__(256, 2)
void vacf_accum(const float* __restrict__ X, float* __restrict__ partial) {
    const int tid  = threadIdx.x;
    const int lane = tid & 63;
    const int wv   = tid >> 6;
    const int j    = blockIdx.x * 256 + tid;
    const bool active = (j < C_DIM);
    const int jj  = active ? j : (C_DIM - 1);   // clamp; inactive zeroed via base
    const float* Xj = X + jj;
    const int t0  = blockIdx.z * WG;            // lag group offset
    const int i00 = blockIdx.y * (CPB * R);     // first base row of segment

    float acc[WG];
    #pragma unroll
    for (int t = 0; t < WG; ++t) acc[t] = 0.f;

    // max row touched = i00 + (CPB-1)*R + t0 + SPAN-1 (same for prefetch path)
    const bool tail = (i00 + (CPB - 1) * R + t0 + SPAN - 1) >= T_DIM;
    if (!tail) segment_work<false>(Xj, i00, t0, active, acc);
    else       segment_work<true >(Xj, i00, t0, active, acc);

    // per-lag wave butterfly -> 4-wave LDS combine -> 1 atomic/lag/block
    __shared__ float part[4][WG];
    #pragma unroll
    for (int tt = 0; tt < WG; ++tt) {
        float v = acc[tt];
        #pragma unroll
        for (int m = 1; m < 64; m <<= 1) v += __shfl_xor(v, m, 64);
        if (lane == 0) part[wv][tt] = v;
    }
    __syncthreads();
    if (tid < WG) {
        float s = part[0][tid] + part[1][tid] + part[2][tid] + part[3][tid];
        atomicAdd(&partial[t0 + tid], s);
    }
}

__global__ void vacf_scale(const float* __restrict__ partial, float* __restrict__ out) {
    int t = threadIdx.x;
    if (t < W) out[t] = partial[t] / ((float)(T_DIM - t) * (float)C_DIM);
}

extern "C" void kernel_launch(void* const* d_in, const int* in_sizes, int n_in,
                              void* d_out, int out_size, void* d_ws, size_t ws_size,
                              hipStream_t stream) {
    const float* X = (const float*)d_in[0];
    float* out = (float*)d_out;
    float* ws  = (float*)d_ws;

    hipMemsetAsync(ws, 0, W * sizeof(float), stream);
    dim3 grid(NCGRP, NSEG, NG);
    vacf_accum<<<grid, 256, 0, stream>>>(X, ws);
    vacf_scale<<<1, 128, 0, stream>>>(ws, out);
}

// Round 7
// 287.984 us; speedup vs baseline: 16.9310x; 1.0890x over previous
//
#include <hip/hip_runtime.h>

// VACF: vel [T=10000, N=1000, 3] fp32, window W=100.
// out[t] = sum_{i<T-t} sum_j x[i][j]*x[i+t][j] / ((T-t)*C),  C = 3000.
//
// Round 7: R6 pipelining was correct but stalls remained because lag group
// was the SLOWEST grid dim: 4 groups swept the data at separated times,
// L3 evicted between sweeps -> FETCH 470MB = 4x dataset, ~900cyc HBM-miss
// latency vs ~800cyc pipeline lead. Fix: fold group into blockIdx.x so all
// 4 groups of a segment run concurrently and share L2/L3 (window ranges
// overlap 75%, base rows identical). Also defer inactive-lane masking to
// the epilogue (kills 16 cndmask/chunk chained onto loads).

#define T_DIM 10000
#define C_DIM 3000
#define W 100
#define WG 25          // lags per lag-group
#define NG 4           // lag groups; NG*WG == W
#define R 16           // base rows per chunk
#define SPAN 40        // window span = R + WG - 1
#define CPB 5          // contiguous chunks per block
#define NSEG 125       // (T_DIM/R) / CPB
#define NCGRP 12       // ceil(C_DIM / 256)

template <bool CHECKED>
__device__ __forceinline__ float wload(const float* __restrict__ Xj, int row) {
    // row is wave-uniform; row*C_DIM fits in int
    return (!CHECKED || row < T_DIM) ? Xj[row * C_DIM] : 0.f;
}

template <bool CHECKED>
__device__ __forceinline__ void segment_work(const float* __restrict__ Xj,
                                             int i00, int t0,
                                             float* __restrict__ acc) {
    float win[SPAN], base[R], nbase[R], nfresh[R];

    // prologue (only unhidden loads: once per segment)
    #pragma unroll
    for (int q = 0; q < SPAN; ++q)
        win[q] = wload<CHECKED>(Xj, i00 + t0 + q);
    #pragma unroll
    for (int r = 0; r < R; ++r)
        base[r] = Xj[(i00 + r) * C_DIM];       // base rows always < T_DIM

    #pragma unroll 1
    for (int c = 0; c < CPB; ++c) {
        const int i0 = i00 + c * R;
        const bool more = (c + 1 < CPB);

        // ---- prefetch chunk c+1 (consumed after this chunk's 400 FMAs) ----
        if (more) {
            #pragma unroll
            for (int r = 0; r < R; ++r)
                nbase[r] = Xj[(i0 + R + r) * C_DIM];      // next base, < T_DIM
            #pragma unroll
            for (int q = 0; q < R; ++q)                   // next fresh window rows
                nfresh[q] = wload<CHECKED>(Xj, i0 + R + t0 + (SPAN - R) + q);
        }

        // ---- 400 FMAs on fully-resident registers ----
        #pragma unroll
        for (int tt = 0; tt < WG; ++tt) {
            #pragma unroll
            for (int r = 0; r < R; ++r)
                acc[tt] += base[r] * win[tt + r];
        }

        // ---- rotate pipeline registers ----
        if (more) {
            #pragma unroll
            for (int q = 0; q < SPAN - R; ++q) win[q] = win[q + R];
            #pragma unroll
            for (int q = 0; q < R; ++q) win[SPAN - R + q] = nfresh[q];
            #pragma unroll
            for (int r = 0; r < R; ++r) base[r] = nbase[r];
        }
    }
}

__global__ __launch_bounds__(256, 2)
void vacf_accum(const float* __restrict__ X, float* __restrict__ partial) {
    const int tid  = threadIdx.x;
    const int lane = tid & 63;
    const int wv   = tid >> 6;
    const int cg   = blockIdx.x % NCGRP;        // column group (fast: locality)
    const int g    = blockIdx.x / NCGRP;        // lag group (adjacent in dispatch)
    const int j    = cg * 256 + tid;
    const bool active = (j < C_DIM);
    const int jj  = active ? j : (C_DIM - 1);   // clamp; garbage discarded in epilogue
    const float* Xj = X + jj;
    const int t0  = g * WG;                     // lag group offset
    const int i00 = blockIdx.y * (CPB * R);     // first base row of segment

    float acc[WG];
    #pragma unroll
    for (int t = 0; t < WG; ++t) acc[t] = 0.f;

    // max row touched = i00 + (CPB-1)*R + t0 + SPAN-1 (same for prefetch path)
    const bool tail = (i00 + (CPB - 1) * R + t0 + SPAN - 1) >= T_DIM;
    if (!tail) segment_work<false>(Xj, i00, t0, acc);
    else       segment_work<true >(Xj, i00, t0, acc);

    // discard inactive lanes (deferred mask), then reduce
    if (!active) {
        #pragma unroll
        for (int tt = 0; tt < WG; ++tt) acc[tt] = 0.f;
    }

    // per-lag wave butterfly -> 4-wave LDS combine -> 1 atomic/lag/block
    __shared__ float part[4][WG];
    #pragma unroll
    for (int tt = 0; tt < WG; ++tt) {
        float v = acc[tt];
        #pragma unroll
        for (int m = 1; m < 64; m <<= 1) v += __shfl_xor(v, m, 64);
        if (lane == 0) part[wv][tt] = v;
    }
    __syncthreads();
    if (tid < WG) {
        float s = part[0][tid] + part[1][tid] + part[2][tid] + part[3][tid];
        atomicAdd(&partial[t0 + tid], s);
    }
}

__global__ void vacf_scale(const float* __restrict__ partial, float* __restrict__ out) {
    int t = threadIdx.x;
    if (t < W) out[t] = partial[t] / ((float)(T_DIM - t) * (float)C_DIM);
}

extern "C" void kernel_launch(void* const* d_in, const int* in_sizes, int n_in,
                              void* d_out, int out_size, void* d_ws, size_t ws_size,
                              hipStream_t stream) {
    const float* X = (const float*)d_in[0];
    float* out = (float*)d_out;
    float* ws  = (float*)d_ws;

    hipMemsetAsync(ws, 0, W * sizeof(float), stream);
    dim3 grid(NCGRP * NG, NSEG);
    vacf_accum<<<grid, 256, 0, stream>>>(X, ws);
    vacf_scale<<<1, 128, 0, stream>>>(ws, out);
}